// Round 1
// baseline (2074.324 us; speedup 1.0000x reference)
//
#include <hip/hip_runtime.h>

#define HIDDEN 64
#define NB 32

// One wave (64 lanes) per edge; lane = hidden channel.
// Both MLPs (scalar & vector) computed together with float2-interleaved
// weights in LDS. Scatter via global fp32 atomics (device scope).
__global__ __launch_bounds__(256) void tpconv_edge_kernel(
    const float* __restrict__ scalar,       // [N,64]
    const float* __restrict__ vector,       // [N,3,64]
    const float* __restrict__ edge_length,  // [E,32]
    const int*   __restrict__ edge_index,   // [2,E]
    const float* __restrict__ sw1, const float* __restrict__ sb1,
    const float* __restrict__ sw2, const float* __restrict__ sb2,
    const float* __restrict__ vw1, const float* __restrict__ vb1,
    const float* __restrict__ vw2, const float* __restrict__ vb2,
    float* __restrict__ out_scalar,         // [N,64]
    float* __restrict__ out_vector,         // [N,3,64]
    int E)
{
    // Interleave scalar-MLP and vector-MLP weights as float2 -> one ds_read_b64
    // per k feeds both FMAs.
    __shared__ float2 w1s[NB * HIDDEN];       // 16 KB  [k][i] = (sw1, vw1)
    __shared__ float2 w2s[HIDDEN * HIDDEN];   // 32 KB  [k][i] = (sw2, vw2)
    __shared__ float2 b1s[HIDDEN];            // (sb1, vb1)
    __shared__ float2 b2s[HIDDEN];            // (sb2, vb2)

    const int t = threadIdx.x;
    for (int idx = t; idx < NB * HIDDEN; idx += 256)
        w1s[idx] = make_float2(sw1[idx], vw1[idx]);
    for (int idx = t; idx < HIDDEN * HIDDEN; idx += 256)
        w2s[idx] = make_float2(sw2[idx], vw2[idx]);
    if (t < HIDDEN) {
        b1s[t] = make_float2(sb1[t], vb1[t]);
        b2s[t] = make_float2(sb2[t], vb2[t]);
    }
    __syncthreads();

    const int lane   = t & 63;
    const int wave   = blockIdx.x * (blockDim.x >> 6) + (t >> 6);
    const int nwaves = gridDim.x * (blockDim.x >> 6);

    for (int e = wave; e < E; e += nwaves) {
        const int row = edge_index[e];        // destination (scatter)
        const int col = edge_index[E + e];    // source (gather)

        // lanes 0..31 and 32..63 each hold a copy of the 32 basis values
        const float el = edge_length[e * NB + (lane & 31)];

        // ---- layer 1: [32] @ [32,64] for both MLPs ----
        float hs = b1s[lane].x;
        float hv = b1s[lane].y;
        #pragma unroll
        for (int k = 0; k < NB; ++k) {
            const float ek = __shfl(el, k, 64);
            const float2 w = w1s[k * HIDDEN + lane];
            hs = fmaf(ek, w.x, hs);
            hv = fmaf(ek, w.y, hv);
        }

        // SiLU
        hs = hs / (1.0f + __expf(-hs));
        hv = hv / (1.0f + __expf(-hv));

        // ---- layer 2: [64] @ [64,64] for both MLPs ----
        float ows = b2s[lane].x;
        float owv = b2s[lane].y;
        #pragma unroll
        for (int k = 0; k < HIDDEN; ++k) {
            const float hsk = __shfl(hs, k, 64);
            const float hvk = __shfl(hv, k, 64);
            const float2 w = w2s[k * HIDDEN + lane];
            ows = fmaf(hsk, w.x, ows);
            owv = fmaf(hvk, w.y, owv);
        }

        // ---- gather, weight, scatter-add ----
        const float s  = scalar[col * HIDDEN + lane];
        const long vb  = (long)col * 3 * HIDDEN;
        const float v0 = vector[vb + 0 * HIDDEN + lane];
        const float v1 = vector[vb + 1 * HIDDEN + lane];
        const float v2 = vector[vb + 2 * HIDDEN + lane];

        atomicAdd(&out_scalar[row * HIDDEN + lane], s * ows);
        const long ob = (long)row * 3 * HIDDEN;
        atomicAdd(&out_vector[ob + 0 * HIDDEN + lane], v0 * owv);
        atomicAdd(&out_vector[ob + 1 * HIDDEN + lane], v1 * owv);
        atomicAdd(&out_vector[ob + 2 * HIDDEN + lane], v2 * owv);
    }
}

extern "C" void kernel_launch(void* const* d_in, const int* in_sizes, int n_in,
                              void* d_out, int out_size, void* d_ws, size_t ws_size,
                              hipStream_t stream) {
    const float* scalar      = (const float*)d_in[0];
    const float* vector      = (const float*)d_in[1];
    // d_in[2] = edge_sh (unused by reference)
    const float* edge_length = (const float*)d_in[3];
    const int*   edge_index  = (const int*)d_in[4];
    const float* sw1 = (const float*)d_in[5];
    const float* sb1 = (const float*)d_in[6];
    const float* sw2 = (const float*)d_in[7];
    const float* sb2 = (const float*)d_in[8];
    const float* vw1 = (const float*)d_in[9];
    const float* vb1 = (const float*)d_in[10];
    const float* vw2 = (const float*)d_in[11];
    const float* vb2 = (const float*)d_in[12];

    const int N = in_sizes[0] / HIDDEN;       // 50000
    const int E = in_sizes[4] / 2;            // 500000

    float* out_scalar = (float*)d_out;                 // [N,64]
    float* out_vector = (float*)d_out + (size_t)N * HIDDEN; // [N,3,64]

    // Output buffer is poisoned before every launch -> zero it (accumulators).
    hipMemsetAsync(d_out, 0, (size_t)out_size * sizeof(float), stream);

    const int block = 256;                    // 4 waves/block
    const int grid  = 3072;                   // grid-stride over 500k edges
    tpconv_edge_kernel<<<grid, block, 0, stream>>>(
        scalar, vector, edge_length, edge_index,
        sw1, sb1, sw2, sb2, vw1, vb1, vw2, vb2,
        out_scalar, out_vector, E);
}

// Round 2
// 1997.491 us; speedup vs baseline: 1.0385x; 1.0385x over previous
//
#include <hip/hip_runtime.h>

#define HIDDEN 64
#define NB 32
#define SCAN_BLOCK 1024

// ---------------------------------------------------------------------------
// CSR build: histogram -> block scan -> global scan -> scatter permutation.
// Then one wave per destination node accumulates its edges in registers.
// No fp32 atomics anywhere; output written exactly once.
// ---------------------------------------------------------------------------

__global__ __launch_bounds__(256) void hist_kernel(
    const int* __restrict__ edge_index, int* __restrict__ counts, int E)
{
    int i = blockIdx.x * 256 + threadIdx.x;
    if (i < E) atomicAdd(&counts[edge_index[i]], 1);   // row = edge_index[0][i]
}

__global__ __launch_bounds__(SCAN_BLOCK) void scan_pass1(
    const int* __restrict__ counts, int* __restrict__ partial,
    int* __restrict__ blocksums, int N)
{
    __shared__ int tmp[SCAN_BLOCK];
    const int t = threadIdx.x;
    const int gid = blockIdx.x * SCAN_BLOCK + t;
    int v = (gid < N) ? counts[gid] : 0;
    tmp[t] = v;
    __syncthreads();
    for (int off = 1; off < SCAN_BLOCK; off <<= 1) {
        int x = (t >= off) ? tmp[t - off] : 0;
        __syncthreads();
        tmp[t] += x;
        __syncthreads();
    }
    if (gid < N) partial[gid] = tmp[t] - v;            // exclusive
    if (t == SCAN_BLOCK - 1) blocksums[blockIdx.x] = tmp[t];
}

__global__ void scan_pass2(int* __restrict__ blocksums, int nb)
{
    if (threadIdx.x == 0) {
        int acc = 0;
        for (int i = 0; i < nb; ++i) { int v = blocksums[i]; blocksums[i] = acc; acc += v; }
    }
}

__global__ __launch_bounds__(SCAN_BLOCK) void scan_pass3(
    const int* __restrict__ partial, const int* __restrict__ blocksums,
    int* __restrict__ offsets, int* __restrict__ cursors, int N, int E)
{
    const int gid = blockIdx.x * SCAN_BLOCK + threadIdx.x;
    if (gid < N) {
        int o = partial[gid] + blocksums[blockIdx.x];
        offsets[gid] = o;
        cursors[gid] = o;
    }
    if (gid == N) offsets[N] = E;
    else if (gid < N) { /* nothing */ }
    if (blockIdx.x == 0 && threadIdx.x == 0) offsets[N] = E;  // ensure set even if N%SCAN_BLOCK==0 edge case
}

__global__ __launch_bounds__(256) void scatter_kernel(
    const int* __restrict__ edge_index, int* __restrict__ cursors,
    int* __restrict__ perm, int E)
{
    int i = blockIdx.x * 256 + threadIdx.x;
    if (i < E) {
        int pos = atomicAdd(&cursors[edge_index[i]], 1);
        perm[pos] = i;
    }
}

// One wave per node (grid-stride). lane = hidden channel.
__global__ __launch_bounds__(256) void tpconv_node_kernel(
    const float* __restrict__ scalar,       // [N,64]
    const float* __restrict__ vector,       // [N,3,64]
    const float* __restrict__ edge_length,  // [E,32]
    const int*   __restrict__ edge_index,   // [2,E]
    const int*   __restrict__ offsets,      // [N+1]
    const int*   __restrict__ perm,         // [E]
    const float* __restrict__ sw1, const float* __restrict__ sb1,
    const float* __restrict__ sw2, const float* __restrict__ sb2,
    const float* __restrict__ vw1, const float* __restrict__ vb1,
    const float* __restrict__ vw2, const float* __restrict__ vb2,
    float* __restrict__ out_scalar,         // [N,64]
    float* __restrict__ out_vector,         // [N,3,64]
    int N, int E)
{
    __shared__ float2 w1s[NB * HIDDEN];       // 16 KB  (sw1, vw1)
    __shared__ float2 w2s[HIDDEN * HIDDEN];   // 32 KB  (sw2, vw2)
    __shared__ float2 b1s[HIDDEN];
    __shared__ float2 b2s[HIDDEN];

    const int t = threadIdx.x;
    for (int idx = t; idx < NB * HIDDEN; idx += 256)
        w1s[idx] = make_float2(sw1[idx], vw1[idx]);
    for (int idx = t; idx < HIDDEN * HIDDEN; idx += 256)
        w2s[idx] = make_float2(sw2[idx], vw2[idx]);
    if (t < HIDDEN) {
        b1s[t] = make_float2(sb1[t], vb1[t]);
        b2s[t] = make_float2(sb2[t], vb2[t]);
    }
    __syncthreads();

    const int lane   = t & 63;
    const int wave   = blockIdx.x * (blockDim.x >> 6) + (t >> 6);
    const int nwaves = gridDim.x * (blockDim.x >> 6);

    for (int n = wave; n < N; n += nwaves) {
        const int beg = offsets[n];
        const int end = offsets[n + 1];

        float acc_s  = 0.0f;
        float acc_v0 = 0.0f, acc_v1 = 0.0f, acc_v2 = 0.0f;

        for (int j = beg; j < end; ++j) {
            const int e   = perm[j];           // wave-uniform
            const int col = edge_index[E + e]; // source node

            const float el = edge_length[e * NB + (lane & 31)];

            // layer 1: [32] @ [32,64], both MLPs
            float hs = b1s[lane].x;
            float hv = b1s[lane].y;
            #pragma unroll
            for (int k = 0; k < NB; ++k) {
                const float ek = __shfl(el, k, 64);
                const float2 w = w1s[k * HIDDEN + lane];
                hs = fmaf(ek, w.x, hs);
                hv = fmaf(ek, w.y, hv);
            }
            hs = hs / (1.0f + __expf(-hs));
            hv = hv / (1.0f + __expf(-hv));

            // layer 2: [64] @ [64,64], both MLPs
            float ows = b2s[lane].x;
            float owv = b2s[lane].y;
            #pragma unroll
            for (int k = 0; k < HIDDEN; ++k) {
                const float hsk = __shfl(hs, k, 64);
                const float hvk = __shfl(hv, k, 64);
                const float2 w = w2s[k * HIDDEN + lane];
                ows = fmaf(hsk, w.x, ows);
                owv = fmaf(hvk, w.y, owv);
            }

            const float s  = scalar[(long)col * HIDDEN + lane];
            const long  vb = (long)col * 3 * HIDDEN;
            acc_s  = fmaf(s, ows, acc_s);
            acc_v0 = fmaf(vector[vb + 0 * HIDDEN + lane], owv, acc_v0);
            acc_v1 = fmaf(vector[vb + 1 * HIDDEN + lane], owv, acc_v1);
            acc_v2 = fmaf(vector[vb + 2 * HIDDEN + lane], owv, acc_v2);
        }

        out_scalar[(long)n * HIDDEN + lane] = acc_s;
        const long ob = (long)n * 3 * HIDDEN;
        out_vector[ob + 0 * HIDDEN + lane] = acc_v0;
        out_vector[ob + 1 * HIDDEN + lane] = acc_v1;
        out_vector[ob + 2 * HIDDEN + lane] = acc_v2;
    }
}

extern "C" void kernel_launch(void* const* d_in, const int* in_sizes, int n_in,
                              void* d_out, int out_size, void* d_ws, size_t ws_size,
                              hipStream_t stream) {
    const float* scalar      = (const float*)d_in[0];
    const float* vector      = (const float*)d_in[1];
    // d_in[2] = edge_sh (unused)
    const float* edge_length = (const float*)d_in[3];
    const int*   edge_index  = (const int*)d_in[4];
    const float* sw1 = (const float*)d_in[5];
    const float* sb1 = (const float*)d_in[6];
    const float* sw2 = (const float*)d_in[7];
    const float* sb2 = (const float*)d_in[8];
    const float* vw1 = (const float*)d_in[9];
    const float* vb1 = (const float*)d_in[10];
    const float* vw2 = (const float*)d_in[11];
    const float* vb2 = (const float*)d_in[12];

    const int N = in_sizes[0] / HIDDEN;       // 50000
    const int E = in_sizes[4] / 2;            // 500000

    float* out_scalar = (float*)d_out;
    float* out_vector = (float*)d_out + (size_t)N * HIDDEN;

    // workspace layout (ints)
    int* ws        = (int*)d_ws;
    int* counts    = ws;                       // [N]
    int* partial   = ws + N;                   // [N]
    int* offsets   = ws + 2 * N;               // [N+1]
    int* cursors   = ws + 3 * N + 1;           // [N]
    int* blocksums = ws + 4 * N + 1;           // [64]
    int* perm      = ws + 4 * N + 1 + 64;      // [E]

    hipMemsetAsync(counts, 0, (size_t)N * sizeof(int), stream);

    const int egrid = (E + 255) / 256;
    hist_kernel<<<egrid, 256, 0, stream>>>(edge_index, counts, E);

    const int nb = (N + SCAN_BLOCK - 1) / SCAN_BLOCK;   // 49
    scan_pass1<<<nb, SCAN_BLOCK, 0, stream>>>(counts, partial, blocksums, N);
    scan_pass2<<<1, 64, 0, stream>>>(blocksums, nb);
    scan_pass3<<<nb, SCAN_BLOCK, 0, stream>>>(partial, blocksums, offsets, cursors, N, E);

    scatter_kernel<<<egrid, 256, 0, stream>>>(edge_index, cursors, perm, E);

    // main kernel: one wave per node, grid-stride
    tpconv_node_kernel<<<2048, 256, 0, stream>>>(
        scalar, vector, edge_length, edge_index, offsets, perm,
        sw1, sb1, sw2, sb2, vw1, vb1, vw2, vb2,
        out_scalar, out_vector, N, E);
}

// Round 3
// 1361.795 us; speedup vs baseline: 1.5232x; 1.4668x over previous
//
#include <hip/hip_runtime.h>

#define HIDDEN 64
#define NB 32
#define SCAN_BLOCK 1024

// ---- bf16 helpers (RNE; inputs are well-behaved, no NaN handling needed) ----
static __device__ __forceinline__ unsigned short f2bf(float x) {
    union { float f; unsigned u; } v; v.f = x;
    unsigned r = v.u + 0x7fffu + ((v.u >> 16) & 1u);
    return (unsigned short)(r >> 16);
}
static __device__ __forceinline__ float bf2f(unsigned short s) {
    union { unsigned u; float f; } v; v.u = ((unsigned)s) << 16;
    return v.f;
}

// ---------------------------------------------------------------------------
// CSR build (unchanged structure from round 2): histogram -> scan -> scatter.
// scatter additionally emits perm_col so phase B never touches edge_index.
// ---------------------------------------------------------------------------
__global__ __launch_bounds__(256) void hist_kernel(
    const int* __restrict__ edge_index, int* __restrict__ counts, int E)
{
    int i = blockIdx.x * 256 + threadIdx.x;
    if (i < E) atomicAdd(&counts[edge_index[i]], 1);
}

__global__ __launch_bounds__(SCAN_BLOCK) void scan_pass1(
    const int* __restrict__ counts, int* __restrict__ partial,
    int* __restrict__ blocksums, int N)
{
    __shared__ int tmp[SCAN_BLOCK];
    const int t = threadIdx.x;
    const int gid = blockIdx.x * SCAN_BLOCK + t;
    int v = (gid < N) ? counts[gid] : 0;
    tmp[t] = v;
    __syncthreads();
    for (int off = 1; off < SCAN_BLOCK; off <<= 1) {
        int x = (t >= off) ? tmp[t - off] : 0;
        __syncthreads();
        tmp[t] += x;
        __syncthreads();
    }
    if (gid < N) partial[gid] = tmp[t] - v;
    if (t == SCAN_BLOCK - 1) blocksums[blockIdx.x] = tmp[t];
}

__global__ void scan_pass2(int* __restrict__ blocksums, int nb)
{
    if (threadIdx.x == 0) {
        int acc = 0;
        for (int i = 0; i < nb; ++i) { int v = blocksums[i]; blocksums[i] = acc; acc += v; }
    }
}

__global__ __launch_bounds__(SCAN_BLOCK) void scan_pass3(
    const int* __restrict__ partial, const int* __restrict__ blocksums,
    int* __restrict__ offsets, int* __restrict__ cursors, int N, int E)
{
    const int gid = blockIdx.x * SCAN_BLOCK + threadIdx.x;
    if (gid < N) {
        int o = partial[gid] + blocksums[blockIdx.x];
        offsets[gid] = o;
        cursors[gid] = o;
    }
    if (blockIdx.x == 0 && threadIdx.x == 0) offsets[N] = E;
}

__global__ __launch_bounds__(256) void scatter_kernel(
    const int* __restrict__ edge_index, int* __restrict__ cursors,
    int* __restrict__ perm, int* __restrict__ perm_col, int E)
{
    int i = blockIdx.x * 256 + threadIdx.x;
    if (i < E) {
        int pos = atomicAdd(&cursors[edge_index[i]], 1);
        perm[pos] = i;
        perm_col[pos] = edge_index[E + i];
    }
}

// ---------------------------------------------------------------------------
// Phase A: per-edge MLP as pure VALU GEMM. thread = edge; all weight reads are
// wave-uniform -> scalar loads; el[]/h[]/ow[] fully static in VGPRs.
// Writes bf16 weights in perm order (contiguous for phase B).
// ---------------------------------------------------------------------------
static __device__ __forceinline__ void mlp64(
    const float el[NB],
    const float* __restrict__ w1, const float* __restrict__ b1,
    const float* __restrict__ w2, const float* __restrict__ b2,
    unsigned short* __restrict__ out)   // 64 contiguous bf16, 16B-aligned
{
    float h[HIDDEN];
    #pragma unroll
    for (int i = 0; i < HIDDEN; ++i) h[i] = b1[i];
    #pragma unroll
    for (int k = 0; k < NB; ++k) {
        const float ek = el[k];
        #pragma unroll
        for (int i = 0; i < HIDDEN; ++i)
            h[i] = fmaf(ek, w1[k * HIDDEN + i], h[i]);
    }
    #pragma unroll
    for (int i = 0; i < HIDDEN; ++i)
        h[i] = h[i] / (1.0f + __expf(-h[i]));

    #pragma unroll
    for (int c = 0; c < 4; ++c) {               // 16 outputs per chunk
        float ow[16];
        #pragma unroll
        for (int ii = 0; ii < 16; ++ii) ow[ii] = b2[c * 16 + ii];
        #pragma unroll
        for (int k = 0; k < HIDDEN; ++k) {
            const float hk = h[k];
            #pragma unroll
            for (int ii = 0; ii < 16; ++ii)
                ow[ii] = fmaf(hk, w2[k * HIDDEN + c * 16 + ii], ow[ii]);
        }
        unsigned pk[8];
        #pragma unroll
        for (int m = 0; m < 8; ++m)
            pk[m] = (unsigned)f2bf(ow[2 * m]) | ((unsigned)f2bf(ow[2 * m + 1]) << 16);
        uint4* o = (uint4*)(out + c * 16);
        o[0] = make_uint4(pk[0], pk[1], pk[2], pk[3]);
        o[1] = make_uint4(pk[4], pk[5], pk[6], pk[7]);
    }
}

__global__ __launch_bounds__(256) void mlp_kernel(
    const float* __restrict__ edge_length,
    const int* __restrict__ perm,
    const float* __restrict__ sw1, const float* __restrict__ sb1,
    const float* __restrict__ sw2, const float* __restrict__ sb2,
    const float* __restrict__ vw1, const float* __restrict__ vb1,
    const float* __restrict__ vw2, const float* __restrict__ vb2,
    unsigned short* __restrict__ Ws, unsigned short* __restrict__ Wv,
    int E)
{
    const int j = blockIdx.x * 256 + threadIdx.x;
    if (j >= E) return;
    const int e = perm[j];

    float el[NB];
    const float4* p = (const float4*)(edge_length + (size_t)e * NB);
    #pragma unroll
    for (int i = 0; i < NB / 4; ++i) {
        float4 v = p[i];
        el[4 * i + 0] = v.x; el[4 * i + 1] = v.y;
        el[4 * i + 2] = v.z; el[4 * i + 3] = v.w;
    }
    mlp64(el, sw1, sb1, sw2, sb2, Ws + (size_t)j * HIDDEN);
    mlp64(el, vw1, vb1, vw2, vb2, Wv + (size_t)j * HIDDEN);
}

// ---------------------------------------------------------------------------
// Phase B: one wave per destination node; lane = channel. Pure gather-FMA.
// All edge-side reads (Ws/Wv/perm_col) are contiguous in j.
// ---------------------------------------------------------------------------
__global__ __launch_bounds__(256) void node_kernel(
    const float* __restrict__ scalar,       // [N,64]
    const float* __restrict__ vector,       // [N,3,64]
    const int* __restrict__ offsets,        // [N+1]
    const int* __restrict__ perm_col,       // [E]
    const unsigned short* __restrict__ Ws,  // [E,64] bf16
    const unsigned short* __restrict__ Wv,  // [E,64] bf16
    float* __restrict__ out_scalar,         // [N,64]
    float* __restrict__ out_vector,         // [N,3,64]
    int N)
{
    const int lane = threadIdx.x & 63;
    const int wave = blockIdx.x * 4 + (threadIdx.x >> 6);
    const int nw   = gridDim.x * 4;

    for (int n = wave; n < N; n += nw) {
        const int beg = offsets[n];
        const int end = offsets[n + 1];

        float as = 0.0f, a0 = 0.0f, a1 = 0.0f, a2 = 0.0f;

        for (int j = beg; j < end; ++j) {
            const int col = perm_col[j];                // wave-uniform
            const float w_s = bf2f(Ws[(size_t)j * HIDDEN + lane]);
            const float w_v = bf2f(Wv[(size_t)j * HIDDEN + lane]);
            const float* sp = scalar + (size_t)col * HIDDEN;
            const float* vp = vector + (size_t)col * 3 * HIDDEN;
            as = fmaf(sp[lane],       w_s, as);
            a0 = fmaf(vp[lane],       w_v, a0);
            a1 = fmaf(vp[64 + lane],  w_v, a1);
            a2 = fmaf(vp[128 + lane], w_v, a2);
        }

        out_scalar[(size_t)n * HIDDEN + lane] = as;
        float* ov = out_vector + (size_t)n * 3 * HIDDEN;
        ov[lane]       = a0;
        ov[64 + lane]  = a1;
        ov[128 + lane] = a2;
    }
}

extern "C" void kernel_launch(void* const* d_in, const int* in_sizes, int n_in,
                              void* d_out, int out_size, void* d_ws, size_t ws_size,
                              hipStream_t stream) {
    const float* scalar      = (const float*)d_in[0];
    const float* vector      = (const float*)d_in[1];
    // d_in[2] = edge_sh (unused by reference)
    const float* edge_length = (const float*)d_in[3];
    const int*   edge_index  = (const int*)d_in[4];
    const float* sw1 = (const float*)d_in[5];
    const float* sb1 = (const float*)d_in[6];
    const float* sw2 = (const float*)d_in[7];
    const float* sb2 = (const float*)d_in[8];
    const float* vw1 = (const float*)d_in[9];
    const float* vb1 = (const float*)d_in[10];
    const float* vw2 = (const float*)d_in[11];
    const float* vb2 = (const float*)d_in[12];

    const int N = in_sizes[0] / HIDDEN;       // 50000
    const int E = in_sizes[4] / 2;            // 500000

    float* out_scalar = (float*)d_out;
    float* out_vector = (float*)d_out + (size_t)N * HIDDEN;

    // ---- workspace layout ----
    // [0, 128 MB): bf16 weight tables Ws, Wv (perm order)
    unsigned short* Ws = (unsigned short*)d_ws;                    // E*64 bf16
    unsigned short* Wv = Ws + (size_t)E * HIDDEN;                  // E*64 bf16
    int* ib = (int*)((char*)d_ws + (size_t)E * HIDDEN * 2 * 2);    // int region
    int* counts    = ib;                        // [N]
    int* partial   = ib + N;                    // [N]
    int* offsets   = ib + 2 * N;                // [N+1]
    int* cursors   = ib + 3 * N + 1;            // [N]
    int* blocksums = ib + 4 * N + 1;            // [64]
    int* perm      = ib + 4 * N + 1 + 64;       // [E]
    int* perm_col  = perm + E;                  // [E]

    hipMemsetAsync(counts, 0, (size_t)N * sizeof(int), stream);

    const int egrid = (E + 255) / 256;
    hist_kernel<<<egrid, 256, 0, stream>>>(edge_index, counts, E);

    const int nb = (N + SCAN_BLOCK - 1) / SCAN_BLOCK;
    scan_pass1<<<nb, SCAN_BLOCK, 0, stream>>>(counts, partial, blocksums, N);
    scan_pass2<<<1, 64, 0, stream>>>(blocksums, nb);
    scan_pass3<<<nb, SCAN_BLOCK, 0, stream>>>(partial, blocksums, offsets, cursors, N, E);

    scatter_kernel<<<egrid, 256, 0, stream>>>(edge_index, cursors, perm, perm_col, E);

    // Phase A: per-edge MLP weights (perm-ordered, bf16)
    mlp_kernel<<<egrid, 256, 0, stream>>>(
        edge_length, perm,
        sw1, sb1, sw2, sb2, vw1, vb1, vw2, vb2,
        Ws, Wv, E);

    // Phase B: wave per node
    const int ngrid = (N + 3) / 4;     // 4 waves per block, one wave per node
    node_kernel<<<ngrid, 256, 0, stream>>>(
        scalar, vector, offsets, perm_col, Ws, Wv,
        out_scalar, out_vector, N);
}

// Round 4
// 375.890 us; speedup vs baseline: 5.5184x; 3.6229x over previous
//
#include <hip/hip_runtime.h>

#define HIDDEN 64
#define NB 32
#define SCAN_BLOCK 1024
#define HSTR 72   // LDS H-tile row stride in shorts: %8==0 (b128 align), not %16 (bank spread)

typedef __attribute__((ext_vector_type(8))) short bf16x8;
typedef __attribute__((ext_vector_type(4))) float f32x4;

// ---- bf16 helpers (RNE) ----
static __device__ __forceinline__ unsigned short f2bf(float x) {
    union { float f; unsigned u; } v; v.f = x;
    unsigned r = v.u + 0x7fffu + ((v.u >> 16) & 1u);
    return (unsigned short)(r >> 16);
}
static __device__ __forceinline__ float bf2f(unsigned short s) {
    union { unsigned u; float f; } v; v.u = ((unsigned)s) << 16;
    return v.f;
}

// ---------------------------------------------------------------------------
// CSR build: histogram -> scan -> scatter (perm + perm_col).
// ---------------------------------------------------------------------------
__global__ __launch_bounds__(256) void hist_kernel(
    const int* __restrict__ edge_index, int* __restrict__ counts, int E)
{
    int i = blockIdx.x * 256 + threadIdx.x;
    if (i < E) atomicAdd(&counts[edge_index[i]], 1);
}

__global__ __launch_bounds__(SCAN_BLOCK) void scan_pass1(
    const int* __restrict__ counts, int* __restrict__ partial,
    int* __restrict__ blocksums, int N)
{
    __shared__ int tmp[SCAN_BLOCK];
    const int t = threadIdx.x;
    const int gid = blockIdx.x * SCAN_BLOCK + t;
    int v = (gid < N) ? counts[gid] : 0;
    tmp[t] = v;
    __syncthreads();
    for (int off = 1; off < SCAN_BLOCK; off <<= 1) {
        int x = (t >= off) ? tmp[t - off] : 0;
        __syncthreads();
        tmp[t] += x;
        __syncthreads();
    }
    if (gid < N) partial[gid] = tmp[t] - v;
    if (t == SCAN_BLOCK - 1) blocksums[blockIdx.x] = tmp[t];
}

__global__ void scan_pass2(int* __restrict__ blocksums, int nb)
{
    if (threadIdx.x == 0) {
        int acc = 0;
        for (int i = 0; i < nb; ++i) { int v = blocksums[i]; blocksums[i] = acc; acc += v; }
    }
}

__global__ __launch_bounds__(SCAN_BLOCK) void scan_pass3(
    const int* __restrict__ partial, const int* __restrict__ blocksums,
    int* __restrict__ offsets, int* __restrict__ cursors, int N, int E)
{
    const int gid = blockIdx.x * SCAN_BLOCK + threadIdx.x;
    if (gid < N) {
        int o = partial[gid] + blocksums[blockIdx.x];
        offsets[gid] = o;
        cursors[gid] = o;
    }
    if (blockIdx.x == 0 && threadIdx.x == 0) offsets[N] = E;
}

__global__ __launch_bounds__(256) void scatter_kernel(
    const int* __restrict__ edge_index, int* __restrict__ cursors,
    int* __restrict__ perm, int* __restrict__ perm_col, int E)
{
    int i = blockIdx.x * 256 + threadIdx.x;
    if (i < E) {
        int pos = atomicAdd(&cursors[edge_index[i]], 1);
        perm[pos] = i;
        perm_col[pos] = edge_index[E + i];
    }
}

// ---------------------------------------------------------------------------
// Phase A (MFMA): per-edge MLP weights via matrix cores.
// Wave = 64 edges/iter. Weights resident in VGPRs as B-frags.
// mfma_f32_16x16x32_bf16 layouts:
//   A[m][k]: m=lane&15, k=(lane>>4)*8+j        (8 bf16/lane)
//   B[k][n]: n=lane&15, k=(lane>>4)*8+j        (assumed symmetric to A)
//   C/D[row][col]: col=lane&15, row=(lane>>4)*4+r   (verified m89/m91)
// ---------------------------------------------------------------------------
__global__ __launch_bounds__(256) void mlp_mfma_kernel(
    const float* __restrict__ edge_length,   // [E,32]
    const int*   __restrict__ perm,          // [E]
    const float* __restrict__ sw1, const float* __restrict__ sb1,
    const float* __restrict__ sw2, const float* __restrict__ sb2,
    const float* __restrict__ vw1, const float* __restrict__ vb1,
    const float* __restrict__ vw2, const float* __restrict__ vb2,
    unsigned short* __restrict__ Ws,         // [E,64] bf16, perm order
    unsigned short* __restrict__ Wv,         // [E,64] bf16, perm order
    int E, int nchunks)
{
    __shared__ short Hs[4][64 * HSTR];       // per-wave H / output staging (9216 B each)

    const int t    = threadIdx.x;
    const int lane = t & 63;
    const int wid  = t >> 6;
    const int quad = lane >> 4;
    const int l16  = lane & 15;
    short* Hw = Hs[wid];

    const float* w1p[2] = {sw1, vw1};
    const float* b1p[2] = {sb1, vb1};
    const float* w2p[2] = {sw2, vw2};
    const float* b2p[2] = {sb2, vb2};
    unsigned short* outp[2] = {Ws, Wv};

    // ---- preamble: load weight B-frags into VGPRs (once per wave) ----
    bf16x8 w1f[2][4];            // [mlp][ntile]
    bf16x8 w2f[2][2][4];         // [mlp][kstep][ntile]
    float  b1v[2][4], b2v[2][4];
    #pragma unroll
    for (int m = 0; m < 2; ++m) {
        #pragma unroll
        for (int nt = 0; nt < 4; ++nt) {
            const int col = nt * 16 + l16;
            #pragma unroll
            for (int j = 0; j < 8; ++j)
                w1f[m][nt][j] = (short)f2bf(w1p[m][(quad * 8 + j) * HIDDEN + col]);
            #pragma unroll
            for (int kk = 0; kk < 2; ++kk) {
                #pragma unroll
                for (int j = 0; j < 8; ++j)
                    w2f[m][kk][nt][j] = (short)f2bf(w2p[m][(kk * 32 + quad * 8 + j) * HIDDEN + col]);
            }
            b1v[m][nt] = b1p[m][col];
            b2v[m][nt] = b2p[m][col];
        }
    }

    const int wave_g = blockIdx.x * 4 + wid;
    const int nwaves = gridDim.x * 4;

    for (int c = wave_g; c < nchunks; c += nwaves) {
        const int j0 = c * 64;

        // ---- A-frags for EL tile [64 edges x 32 basis] ----
        bf16x8 af[4];
        #pragma unroll
        for (int mt = 0; mt < 4; ++mt) {
            int j = j0 + mt * 16 + l16;
            int e = perm[j < E ? j : (E - 1)];
            const float* r = edge_length + (size_t)e * NB + quad * 8;
            float4 u0 = *(const float4*)r;
            float4 u1 = *(const float4*)(r + 4);
            af[mt][0] = (short)f2bf(u0.x); af[mt][1] = (short)f2bf(u0.y);
            af[mt][2] = (short)f2bf(u0.z); af[mt][3] = (short)f2bf(u0.w);
            af[mt][4] = (short)f2bf(u1.x); af[mt][5] = (short)f2bf(u1.y);
            af[mt][6] = (short)f2bf(u1.z); af[mt][7] = (short)f2bf(u1.w);
        }

        #pragma unroll
        for (int m = 0; m < 2; ++m) {
            // ---- layer 1: [64,32]@[32,64] + bias, SiLU, -> LDS (bf16) ----
            #pragma unroll
            for (int mt = 0; mt < 4; ++mt) {
                #pragma unroll
                for (int nt = 0; nt < 4; ++nt) {
                    f32x4 cf = {b1v[m][nt], b1v[m][nt], b1v[m][nt], b1v[m][nt]};
                    cf = __builtin_amdgcn_mfma_f32_16x16x32_bf16(af[mt], w1f[m][nt], cf, 0, 0, 0);
                    #pragma unroll
                    for (int r4 = 0; r4 < 4; ++r4) {
                        float x = cf[r4];
                        x = x / (1.0f + __expf(-x));
                        const int row = mt * 16 + quad * 4 + r4;
                        Hw[row * HSTR + nt * 16 + l16] = (short)f2bf(x);
                    }
                }
            }

            // ---- layer 2: [64,64]@[64,64] + bias; result back into LDS ----
            #pragma unroll
            for (int mt = 0; mt < 4; ++mt) {
                const int arow = mt * 16 + l16;
                bf16x8 a0 = *(const bf16x8*)(Hw + arow * HSTR + quad * 8);
                bf16x8 a1 = *(const bf16x8*)(Hw + arow * HSTR + 32 + quad * 8);
                #pragma unroll
                for (int nt = 0; nt < 4; ++nt) {
                    f32x4 cf = {b2v[m][nt], b2v[m][nt], b2v[m][nt], b2v[m][nt]};
                    cf = __builtin_amdgcn_mfma_f32_16x16x32_bf16(a1, w2f[m][1][nt], cf, 0, 0, 0);
                    cf = __builtin_amdgcn_mfma_f32_16x16x32_bf16(a0, w2f[m][0][nt], cf, 0, 0, 0);
                    #pragma unroll
                    for (int r4 = 0; r4 < 4; ++r4) {
                        const int row = mt * 16 + quad * 4 + r4;
                        Hw[row * HSTR + nt * 16 + l16] = (short)f2bf(cf[r4]);
                    }
                }
            }

            // ---- coalesced store: LDS -> global (16 B/lane, 1 KB/instr) ----
            unsigned short* op = outp[m] + (size_t)j0 * HIDDEN;
            #pragma unroll
            for (int i = 0; i < 8; ++i) {
                const int row = i * 8 + (lane >> 3);
                bf16x8 v = *(const bf16x8*)(Hw + row * HSTR + (lane & 7) * 8);
                if (j0 + row < E)
                    *(bf16x8*)(op + (size_t)i * 512 + lane * 8) = v;
            }
        }
    }
}

// ---------------------------------------------------------------------------
// Phase B: one wave per destination node; lane = channel. Pure gather-FMA.
// ---------------------------------------------------------------------------
__global__ __launch_bounds__(256) void node_kernel(
    const float* __restrict__ scalar,       // [N,64]
    const float* __restrict__ vector,       // [N,3,64]
    const int* __restrict__ offsets,        // [N+1]
    const int* __restrict__ perm_col,       // [E]
    const unsigned short* __restrict__ Ws,  // [E,64] bf16
    const unsigned short* __restrict__ Wv,  // [E,64] bf16
    float* __restrict__ out_scalar,         // [N,64]
    float* __restrict__ out_vector,         // [N,3,64]
    int N)
{
    const int lane = threadIdx.x & 63;
    const int wave = blockIdx.x * 4 + (threadIdx.x >> 6);
    const int nw   = gridDim.x * 4;

    for (int n = wave; n < N; n += nw) {
        const int beg = offsets[n];
        const int end = offsets[n + 1];

        float as = 0.0f, a0 = 0.0f, a1 = 0.0f, a2 = 0.0f;

        for (int j = beg; j < end; ++j) {
            const int col = perm_col[j];                // wave-uniform
            const float w_s = bf2f(Ws[(size_t)j * HIDDEN + lane]);
            const float w_v = bf2f(Wv[(size_t)j * HIDDEN + lane]);
            const float* sp = scalar + (size_t)col * HIDDEN;
            const float* vp = vector + (size_t)col * 3 * HIDDEN;
            as = fmaf(sp[lane],       w_s, as);
            a0 = fmaf(vp[lane],       w_v, a0);
            a1 = fmaf(vp[64 + lane],  w_v, a1);
            a2 = fmaf(vp[128 + lane], w_v, a2);
        }

        out_scalar[(size_t)n * HIDDEN + lane] = as;
        float* ov = out_vector + (size_t)n * 3 * HIDDEN;
        ov[lane]       = a0;
        ov[64 + lane]  = a1;
        ov[128 + lane] = a2;
    }
}

extern "C" void kernel_launch(void* const* d_in, const int* in_sizes, int n_in,
                              void* d_out, int out_size, void* d_ws, size_t ws_size,
                              hipStream_t stream) {
    const float* scalar      = (const float*)d_in[0];
    const float* vector      = (const float*)d_in[1];
    // d_in[2] = edge_sh (unused by reference)
    const float* edge_length = (const float*)d_in[3];
    const int*   edge_index  = (const int*)d_in[4];
    const float* sw1 = (const float*)d_in[5];
    const float* sb1 = (const float*)d_in[6];
    const float* sw2 = (const float*)d_in[7];
    const float* sb2 = (const float*)d_in[8];
    const float* vw1 = (const float*)d_in[9];
    const float* vb1 = (const float*)d_in[10];
    const float* vw2 = (const float*)d_in[11];
    const float* vb2 = (const float*)d_in[12];

    const int N = in_sizes[0] / HIDDEN;       // 50000
    const int E = in_sizes[4] / 2;            // 500000

    float* out_scalar = (float*)d_out;
    float* out_vector = (float*)d_out + (size_t)N * HIDDEN;

    // ---- workspace layout ----
    unsigned short* Ws = (unsigned short*)d_ws;                    // E*64 bf16
    unsigned short* Wv = Ws + (size_t)E * HIDDEN;                  // E*64 bf16
    int* ib = (int*)((char*)d_ws + (size_t)E * HIDDEN * 2 * 2);    // int region
    int* counts    = ib;                        // [N]
    int* partial   = ib + N;                    // [N]
    int* offsets   = ib + 2 * N;                // [N+1]
    int* cursors   = ib + 3 * N + 1;            // [N]
    int* blocksums = ib + 4 * N + 1;            // [64]
    int* perm      = ib + 4 * N + 1 + 64;       // [E]
    int* perm_col  = perm + E;                  // [E]

    hipMemsetAsync(counts, 0, (size_t)N * sizeof(int), stream);

    const int egrid = (E + 255) / 256;
    hist_kernel<<<egrid, 256, 0, stream>>>(edge_index, counts, E);

    const int nb = (N + SCAN_BLOCK - 1) / SCAN_BLOCK;
    scan_pass1<<<nb, SCAN_BLOCK, 0, stream>>>(counts, partial, blocksums, N);
    scan_pass2<<<1, 64, 0, stream>>>(blocksums, nb);
    scan_pass3<<<nb, SCAN_BLOCK, 0, stream>>>(partial, blocksums, offsets, cursors, N, E);

    scatter_kernel<<<egrid, 256, 0, stream>>>(edge_index, cursors, perm, perm_col, E);

    // Phase A: MFMA MLP — 512 blocks * 4 waves = 2048 waves, grid-stride over chunks
    const int nchunks = (E + 63) / 64;
    mlp_mfma_kernel<<<512, 256, 0, stream>>>(
        edge_length, perm,
        sw1, sb1, sw2, sb2, vw1, vb1, vw2, vb2,
        Ws, Wv, E, nchunks);

    // Phase B: wave per node
    const int ngrid = (N + 3) / 4;
    node_kernel<<<ngrid, 256, 0, stream>>>(
        scalar, vector, offsets, perm_col, Ws, Wv,
        out_scalar, out_vector, N);
}